// Round 5
// baseline (233.590 us; speedup 1.0000x reference)
//
#include <hip/hip_runtime.h>
#include <hip/hip_bf16.h>
#include <hip/hip_cooperative_groups.h>
#include <stdint.h>

namespace cg = cooperative_groups;

typedef __attribute__((ext_vector_type(4))) float fx4;
typedef __attribute__((ext_vector_type(16))) float fx16;
typedef __attribute__((ext_vector_type(8))) short bx8;
typedef unsigned short u16;
typedef unsigned int u32;

#define LDW 72          // LDS row stride in u16 (144B)
#define PL (64 * LDW)   // u16 per 64-row plane

// ws layout (bytes):
//   u16 wsP[2][4][4096] @ 0: per gen {rmT_hi, rmT_lo, cmT_hi, cmT_lo}, dense stride 64 (64 KiB)
//   u16 rm_bf[64][4096] @ 65536           (512 KiB)
//   u16 cm_bf[64][4096] @ 65536+524288    (512 KiB)

__device__ __forceinline__ u16 f2bf(float x) {
    u32 u = __float_as_uint(x);
    return (u16)((u + 0x7FFFu + ((u >> 16) & 1u)) >> 16);
}
__device__ __forceinline__ float bf2f(u16 h) { return __uint_as_float(((u32)h) << 16); }

__device__ __forceinline__ bx8 ld32(const u16* p, int band, int kc, int l) {
    return *(const bx8*)(p + (band * 32 + (l & 31)) * LDW + kc * 16 + (l >> 5) * 8);
}

__device__ __forceinline__ void mmS(const u16* z1h, const u16* z1l,
                                    const u16* z2h, const u16* z2l,
                                    int ti, int tj, int l, fx16& acc) {
#pragma unroll
    for (int i = 0; i < 16; ++i) acc[i] = 0.f;
#pragma unroll
    for (int kc = 0; kc < 4; ++kc) {
        bx8 ah = ld32(z1h, ti, kc, l), al = ld32(z1l, ti, kc, l);
        bx8 bh = ld32(z2h, tj, kc, l), bl = ld32(z2l, tj, kc, l);
        acc = __builtin_amdgcn_mfma_f32_32x32x16_bf16(ah, bh, acc, 0, 0, 0);
        acc = __builtin_amdgcn_mfma_f32_32x32x16_bf16(ah, bl, acc, 0, 0, 0);
        acc = __builtin_amdgcn_mfma_f32_32x32x16_bf16(al, bh, acc, 0, 0, 0);
    }
}

__device__ __forceinline__ void mmD(const u16* z1h, const u16* z1l,
                                    const u16* z2h, const u16* z2l,
                                    int ti, int tj, int l, fx16& a1, fx16& a2) {
#pragma unroll
    for (int i = 0; i < 16; ++i) { a1[i] = 0.f; a2[i] = 0.f; }
#pragma unroll
    for (int kc = 0; kc < 4; ++kc) {
        bx8 ah = ld32(z1h, ti, kc, l), al = ld32(z1l, ti, kc, l);
        bx8 bh = ld32(z2h, tj, kc, l), bl = ld32(z2l, tj, kc, l);
        a1 = __builtin_amdgcn_mfma_f32_32x32x16_bf16(ah, bh, a1, 0, 0, 0);
        a1 = __builtin_amdgcn_mfma_f32_32x32x16_bf16(ah, bl, a1, 0, 0, 0);
        a1 = __builtin_amdgcn_mfma_f32_32x32x16_bf16(al, bh, a1, 0, 0, 0);
        a2 = __builtin_amdgcn_mfma_f32_32x32x16_bf16(bh, ah, a2, 0, 0, 0);
        a2 = __builtin_amdgcn_mfma_f32_32x32x16_bf16(bh, al, a2, 0, 0, 0);
        a2 = __builtin_amdgcn_mfma_f32_32x32x16_bf16(bl, ah, a2, 0, 0, 0);
    }
}

__device__ __forceinline__ void stP(u16* hi, u16* lo, int TI, int TJ, int l, const fx16& a) {
    const int Ar = TJ * 32 + (l & 31);
    const int c0 = TI * 32 + 4 * (l >> 5);
#pragma unroll
    for (int q = 0; q < 4; ++q) {
        union { u16 u[4]; uint2 v; } H, L;
#pragma unroll
        for (int r = 0; r < 4; ++r) {
            float v = a[4 * q + r];
            u32 u = __float_as_uint(v);
            H.u[r] = (u16)(u >> 16);
            L.u[r] = f2bf(v - __uint_as_float(u & 0xFFFF0000u));
        }
        *(uint2*)(hi + Ar * LDW + c0 + q * 8) = H.v;
        *(uint2*)(lo + Ar * LDW + c0 + q * 8) = L.v;
    }
}

__device__ __forceinline__ void stG(u16* T, int TI, int TJ, int l, const fx16& a) {
    const int Ar = TJ * 32 + (l & 31);
    const int c0 = TI * 32 + 4 * (l >> 5);
#pragma unroll
    for (int q = 0; q < 4; ++q) {
        union { u16 u[4]; uint2 v; } pk;
#pragma unroll
        for (int r = 0; r < 4; ++r) pk.u[r] = f2bf(a[4 * q + r]);
        *(uint2*)(T + Ar * 64 + c0 + q * 8) = pk.v;
    }
}

__device__ __forceinline__ void epiT32(fx16& a, const float* __restrict__ P,
                                       int TI, int TJ, int l, float qa, float qb) {
    const int gc = TJ * 32 + (l & 31);
    const int r0 = TI * 32 + 4 * (l >> 5);
#pragma unroll
    for (int q = 0; q < 4; ++q)
#pragma unroll
        for (int r = 0; r < 4; ++r) {
            const int gr = r0 + q * 8 + r;
            float m = (P[gc * 64 + gr] - P[gr * 64 + gc]) * 0.03125f;
            a[4 * q + r] += qb * m + (gr == gc ? qa : 0.f);
        }
}
__device__ __forceinline__ void epiN32(fx16& a, const float* __restrict__ P,
                                       int TI, int TJ, int l, float qa, float qb) {
    const int gc = TJ * 32 + (l & 31);
    const int r0 = TI * 32 + 4 * (l >> 5);
#pragma unroll
    for (int q = 0; q < 4; ++q)
#pragma unroll
        for (int r = 0; r < 4; ++r) {
            const int gr = r0 + q * 8 + r;
            float m = (P[gr * 64 + gc] - P[gc * 64 + gr]) * 0.03125f;
            a[4 * q + r] += qb * m + (gr == gc ? qa : 0.f);
        }
}

// One cooperative kernel: phase1 expm (blocks 0-1) -> phase2 tables (blocks 0-63)
// -> phase3 per-token output (all 512 blocks, 8 tokens each).
__global__ __launch_bounds__(256, 2) void fused_kernel(
        const int* __restrict__ tt, const int* __restrict__ tv,
        const int* __restrict__ npos, const float* __restrict__ embed,
        const float* __restrict__ praw, float* __restrict__ out,
        u16* __restrict__ wsP, u16* __restrict__ rm_bf, u16* __restrict__ cm_bf)
{
    __shared__ u16 S[8 * PL];   // 73.7 KB -> 2 blocks/CU
    cg::grid_group grid = cg::this_grid();
    const int bid = blockIdx.x, tid = threadIdx.x;
    const int w = tid >> 6, l = tid & 63;
    const int ti = w & 1, tj = w >> 1;

    // ---------------- PHASE 1: expm (blocks 0,1) ----------------
    if (bid < 2) {
        const int g = bid;
        const float* P = praw + g * 4096;
        u16* p0h = S;            u16* p0l = S + PL;
        u16* p1h = S + 2 * PL;   u16* p1l = S + 3 * PL;
        u16* p2h = S + 4 * PL;   u16* p2l = S + 5 * PL;
        u16* p3h = S + 6 * PL;   u16* p3l = S + 7 * PL;

        for (int s = tid; s < 4096; s += 256) {
            const int r = s >> 6, c = s & 63;
            const float m = (P[r * 64 + c] - P[c * 64 + r]) * 0.03125f;
            u32 um = __float_as_uint(m);
            float lof = m - __uint_as_float(um & 0xFFFF0000u);
            u16 hh = (u16)(um >> 16), ll = f2bf(lof);
            p0h[r * LDW + c] = hh;  p0l[r * LDW + c] = ll;
            p1h[c * LDW + r] = hh;  p1l[c * LDW + r] = ll;
        }
        __syncthreads();

        fx16 acc, a1, a2;

        // step0: Q = M2 -> p2; R0 = C8 I + C9 M -> p3
        mmS(p1h, p1l, p0h, p0l, ti, tj, l, acc);
        stP(p2h, p2l, ti, tj, l, acc);
        {
            const float C8 = 2.48015873015873e-5f, C9 = 2.75573192239859e-6f;
            for (int s = tid; s < 4096; s += 256) {
                const int r = s >> 6, c = s & 63;
                float m = bf2f(p0h[r * LDW + c]) + bf2f(p0l[r * LDW + c]);
                float v = C9 * m + (r == c ? C8 : 0.f);
                u32 u = __float_as_uint(v);
                p3h[r * LDW + c] = (u16)(u >> 16);
                p3l[r * LDW + c] = f2bf(v - __uint_as_float(u & 0xFFFF0000u));
            }
        }
        __syncthreads();

        mmS(p2h, p2l, p3h, p3l, ti, tj, l, acc);
        epiT32(acc, P, ti, tj, l, 1.388888888888889e-3f, 1.984126984126984e-4f);
        stP(p0h, p0l, ti, tj, l, acc);
        __syncthreads();
        mmS(p2h, p2l, p0h, p0l, ti, tj, l, acc);
        epiT32(acc, P, ti, tj, l, 4.166666666666667e-2f, 8.333333333333333e-3f);
        stP(p3h, p3l, ti, tj, l, acc);
        __syncthreads();
        mmS(p2h, p2l, p3h, p3l, ti, tj, l, acc);
        epiT32(acc, P, ti, tj, l, 0.5f, 1.666666666666667e-1f);
        stP(p0h, p0l, ti, tj, l, acc);
        __syncthreads();
        mmD(p2h, p2l, p0h, p0l, ti, tj, l, a1, a2);
        epiT32(a1, P, ti, tj, l, 1.f, 1.f);
        epiN32(a2, P, tj, ti, l, 1.f, 1.f);
        stP(p3h, p3l, ti, tj, l, a1);
        stP(p1h, p1l, tj, ti, l, a2);
        __syncthreads();

        u16 *Ych = p1h, *Ycl = p1l, *Xch = p3h, *Xcl = p3l;
        u16 *Ynh = p2h, *Ynl = p2l, *Xnh = p0h, *Xnl = p0l;
#pragma unroll 1
        for (int s5 = 0; s5 < 5; ++s5) {
            mmD(Ych, Ycl, Xch, Xcl, ti, tj, l, a1, a2);
            stP(Xnh, Xnl, ti, tj, l, a1);
            stP(Ynh, Ynl, tj, ti, l, a2);
            __syncthreads();
            u16* t;
            t = Xch; Xch = Xnh; Xnh = t;   t = Xcl; Xcl = Xnl; Xnl = t;
            t = Ych; Ych = Ynh; Ynh = t;   t = Ycl; Ycl = Ynl; Ynl = t;
        }

        for (int s8 = tid; s8 < 512; s8 += 256) {
            const int base = s8 * 8, r = base >> 6, c = base & 63;
            u16* dst = wsP + g * 16384;
            *(uint4*)(dst + base)         = *(const uint4*)(Ych + r * LDW + c);
            *(uint4*)(dst + 4096 + base)  = *(const uint4*)(Ycl + r * LDW + c);
            *(uint4*)(dst + 8192 + base)  = *(const uint4*)(Xch + r * LDW + c);
            *(uint4*)(dst + 12288 + base) = *(const uint4*)(Xcl + r * LDW + c);
        }
    }
    __threadfence();
    grid.sync();

    // ---------------- PHASE 2: tables (blocks 0..63) ----------------
    if (bid < 64) {
        const int p = bid;
        if (p < 2) {
            for (int s = tid; s < 4096; s += 256) {
                u16 v = ((s >> 6) == (s & 63)) ? (u16)0x3F80 : (u16)0;
                rm_bf[p * 4096 + s] = v;
                cm_bf[p * 4096 + s] = v;
            }
        } else {
            const int d = 31 - __clz(p);
            if (d == 1) {
                const u16* src = wsP + (p & 1) * 16384;
                for (int s = tid; s < 4096; s += 256) {
                    rm_bf[p * 4096 + s] = f2bf(bf2f(src[s]) + bf2f(src[4096 + s]));
                    cm_bf[p * 4096 + s] = f2bf(bf2f(src[8192 + s]) + bf2f(src[12288 + s]));
                }
            } else {
                u16* TAh = S;            u16* TAl = S + PL;
                u16* TBh = S + 2 * PL;   u16* TBl = S + 3 * PL;
                u16* Eah = S + 4 * PL;   u16* Eal = S + 5 * PL;
                u16* Ebh = S + 6 * PL;   u16* Ebl = S + 7 * PL;

                const int b0 = p & 1;
                for (int s8 = tid; s8 < 512; s8 += 256) {
                    const int base = s8 * 8, r = base >> 6, c = base & 63;
                    *(uint4*)(TAh + r * LDW + c) = *(const uint4*)(wsP + 8192 + base);
                    *(uint4*)(TAl + r * LDW + c) = *(const uint4*)(wsP + 12288 + base);
                    *(uint4*)(TBh + r * LDW + c) = *(const uint4*)(wsP + 16384 + 8192 + base);
                    *(uint4*)(TBl + r * LDW + c) = *(const uint4*)(wsP + 16384 + 12288 + base);
                    *(uint4*)(Eah + r * LDW + c) = *(const uint4*)(wsP + b0 * 16384 + base);
                    *(uint4*)(Eal + r * LDW + c) = *(const uint4*)(wsP + b0 * 16384 + 4096 + base);
                }
                __syncthreads();

                fx16 acc, a1, a2;
                u16 *Ech = Eah, *Ecl = Eal, *Enh = Ebh, *Enl = Ebl;
#pragma unroll 1
                for (int j = 1; j <= d - 2; ++j) {
                    const int b = (p >> j) & 1;
                    mmS(b ? TBh : TAh, b ? TBl : TAl, Ech, Ecl, ti, tj, l, acc);
                    stP(Enh, Enl, ti, tj, l, acc);
                    __syncthreads();
                    u16* t;
                    t = Ech; Ech = Enh; Enh = t;   t = Ecl; Ecl = Enl; Enl = t;
                }
                {
                    const int b = (p >> (d - 1)) & 1;
                    mmD(b ? TBh : TAh, b ? TBl : TAl, Ech, Ecl, ti, tj, l, a1, a2);
                    stG(rm_bf + p * 4096, ti, tj, l, a1);
                    stG(cm_bf + p * 4096, tj, ti, l, a2);
                }
            }
        }
    }
    __threadfence();
    grid.sync();

    // ---------------- PHASE 3: per-token output (all blocks, 2 tokens/wave) ----------------
#pragma unroll 1
    for (int t = 0; t < 2; ++t) {
        const int flat = bid * 8 + w * 2 + t;
        const int pos = npos[flat];
        {
            const int ty = tt[flat], v = tv[flat];
            int idx; bool valid = true;
            if (ty == 0)      idx = 0;
            else if (ty == 1) idx = v + 1;
            else if (ty == 2) idx = v + 5;
            else if (ty == 4) idx = 8;
            else if (ty == 3 && v == -1) idx = 10;
            else { idx = 0; valid = false; }
            out[flat * 64 + l] = valid ? embed[idx * 64 + l] : 0.f;
        }

        float* om = out + 4096 * 64 + (size_t)flat * 4096;

        if (pos < 64) {
            const u16* src = rm_bf + pos * 4096;
            for (int e = l * 8; e < 4096; e += 512) {
                uint4 ld = *(const uint4*)(src + e);
                fx4 lo, hi;
                lo[0] = __uint_as_float(ld.x << 16); lo[1] = __uint_as_float(ld.x & 0xFFFF0000u);
                lo[2] = __uint_as_float(ld.y << 16); lo[3] = __uint_as_float(ld.y & 0xFFFF0000u);
                hi[0] = __uint_as_float(ld.z << 16); hi[1] = __uint_as_float(ld.z & 0xFFFF0000u);
                hi[2] = __uint_as_float(ld.w << 16); hi[3] = __uint_as_float(ld.w & 0xFFFF0000u);
                __builtin_nontemporal_store(lo, (fx4*)(om + e));
                __builtin_nontemporal_store(hi, (fx4*)(om + e + 4));
            }
        } else {
            const int lo5 = (pos & 31) | 32;
            const int hi5 = pos >> 5;
            const u16* Acm = cm_bf + hi5 * 4096;
            const u16* Brm = rm_bf + lo5 * 4096;
            const int lr = l & 15, k8 = (l >> 4) * 8;

            bx8 A0[4], A1[4], B0[4], B1[4];
#pragma unroll
            for (int q = 0; q < 4; ++q) {
                A0[q] = *(const bx8*)(Acm + (q * 16 + lr) * 64 + k8);
                A1[q] = *(const bx8*)(Acm + (q * 16 + lr) * 64 + 32 + k8);
            }
#pragma unroll
            for (int c = 0; c < 4; ++c) {
                B0[c] = *(const bx8*)(Brm + (c * 16 + lr) * 64 + k8);
                B1[c] = *(const bx8*)(Brm + (c * 16 + lr) * 64 + 32 + k8);
            }
#pragma unroll
            for (int ct = 0; ct < 4; ++ct) {
#pragma unroll
                for (int q = 0; q < 4; ++q) {
                    fx4 c4 = { 0.f, 0.f, 0.f, 0.f };
                    c4 = __builtin_amdgcn_mfma_f32_16x16x32_bf16(A0[q], B0[ct], c4, 0, 0, 0);
                    c4 = __builtin_amdgcn_mfma_f32_16x16x32_bf16(A1[q], B1[ct], c4, 0, 0, 0);
                    __builtin_nontemporal_store(c4,
                        (fx4*)(om + (ct * 16 + lr) * 64 + q * 16 + 4 * (l >> 4)));
                }
            }
        }
    }
}

extern "C" void kernel_launch(void* const* d_in, const int* in_sizes, int n_in,
                              void* d_out, int out_size, void* d_ws, size_t ws_size,
                              hipStream_t stream)
{
    const int*   tt    = (const int*)d_in[0];
    const int*   tv    = (const int*)d_in[1];
    const int*   np    = (const int*)d_in[2];
    const float* embed = (const float*)d_in[3];
    const float* praw  = (const float*)d_in[4];
    float* out = (float*)d_out;

    u16* wsP   = (u16*)d_ws;
    u16* rm_bf = (u16*)((char*)d_ws + 65536);
    u16* cm_bf = (u16*)((char*)d_ws + 65536 + 524288);

    void* args[] = { (void*)&tt, (void*)&tv, (void*)&np, (void*)&embed,
                     (void*)&praw, (void*)&out, (void*)&wsP, (void*)&rm_bf, (void*)&cm_bf };
    hipLaunchCooperativeKernel((const void*)fused_kernel, dim3(512), dim3(256),
                               args, 0, stream);
}

// Round 6
// 47.733 us; speedup vs baseline: 4.8937x; 4.8937x over previous
//
#include <hip/hip_runtime.h>
#include <hip/hip_bf16.h>
#include <stdint.h>

typedef __attribute__((ext_vector_type(4))) float fx4;
typedef __attribute__((ext_vector_type(16))) float fx16;
typedef __attribute__((ext_vector_type(8))) short bx8;
typedef unsigned short u16;
typedef unsigned int u32;

#define LDW 72          // LDS row stride in u16 (144B)
#define PL (64 * LDW)   // u16 per 64-row plane

// ws layout (bytes):
//   u16 wsP[2][4][4096] @ 0: per gen {rmT_hi, rmT_lo, cmT_hi, cmT_lo}, dense stride 64 (64 KiB)
//   u16 rm_bf[64][4096] @ 65536           (512 KiB)
//   u16 cm_bf[64][4096] @ 65536+524288    (512 KiB)

__device__ __forceinline__ u16 f2bf(float x) {
    u32 u = __float_as_uint(x);
    return (u16)((u + 0x7FFFu + ((u >> 16) & 1u)) >> 16);
}
__device__ __forceinline__ float bf2f(u16 h) { return __uint_as_float(((u32)h) << 16); }

__device__ __forceinline__ bx8 ld32(const u16* p, int band, int kc, int l) {
    return *(const bx8*)(p + (band * 32 + (l & 31)) * LDW + kc * 16 + (l >> 5) * 8);
}

__device__ __forceinline__ void mmS(const u16* z1h, const u16* z1l,
                                    const u16* z2h, const u16* z2l,
                                    int ti, int tj, int l, fx16& acc) {
#pragma unroll
    for (int i = 0; i < 16; ++i) acc[i] = 0.f;
#pragma unroll
    for (int kc = 0; kc < 4; ++kc) {
        bx8 ah = ld32(z1h, ti, kc, l), al = ld32(z1l, ti, kc, l);
        bx8 bh = ld32(z2h, tj, kc, l), bl = ld32(z2l, tj, kc, l);
        acc = __builtin_amdgcn_mfma_f32_32x32x16_bf16(ah, bh, acc, 0, 0, 0);
        acc = __builtin_amdgcn_mfma_f32_32x32x16_bf16(ah, bl, acc, 0, 0, 0);
        acc = __builtin_amdgcn_mfma_f32_32x32x16_bf16(al, bh, acc, 0, 0, 0);
    }
}

__device__ __forceinline__ void mmD(const u16* z1h, const u16* z1l,
                                    const u16* z2h, const u16* z2l,
                                    int ti, int tj, int l, fx16& a1, fx16& a2) {
#pragma unroll
    for (int i = 0; i < 16; ++i) { a1[i] = 0.f; a2[i] = 0.f; }
#pragma unroll
    for (int kc = 0; kc < 4; ++kc) {
        bx8 ah = ld32(z1h, ti, kc, l), al = ld32(z1l, ti, kc, l);
        bx8 bh = ld32(z2h, tj, kc, l), bl = ld32(z2l, tj, kc, l);
        a1 = __builtin_amdgcn_mfma_f32_32x32x16_bf16(ah, bh, a1, 0, 0, 0);
        a1 = __builtin_amdgcn_mfma_f32_32x32x16_bf16(ah, bl, a1, 0, 0, 0);
        a1 = __builtin_amdgcn_mfma_f32_32x32x16_bf16(al, bh, a1, 0, 0, 0);
        a2 = __builtin_amdgcn_mfma_f32_32x32x16_bf16(bh, ah, a2, 0, 0, 0);
        a2 = __builtin_amdgcn_mfma_f32_32x32x16_bf16(bh, al, a2, 0, 0, 0);
        a2 = __builtin_amdgcn_mfma_f32_32x32x16_bf16(bl, ah, a2, 0, 0, 0);
    }
}

__device__ __forceinline__ void stP(u16* hi, u16* lo, int TI, int TJ, int l, const fx16& a) {
    const int Ar = TJ * 32 + (l & 31);
    const int c0 = TI * 32 + 4 * (l >> 5);
#pragma unroll
    for (int q = 0; q < 4; ++q) {
        union { u16 u[4]; uint2 v; } H, L;
#pragma unroll
        for (int r = 0; r < 4; ++r) {
            float v = a[4 * q + r];
            u32 u = __float_as_uint(v);
            H.u[r] = (u16)(u >> 16);
            L.u[r] = f2bf(v - __uint_as_float(u & 0xFFFF0000u));
        }
        *(uint2*)(hi + Ar * LDW + c0 + q * 8) = H.v;
        *(uint2*)(lo + Ar * LDW + c0 + q * 8) = L.v;
    }
}

__device__ __forceinline__ void stG(u16* T, int TI, int TJ, int l, const fx16& a) {
    const int Ar = TJ * 32 + (l & 31);
    const int c0 = TI * 32 + 4 * (l >> 5);
#pragma unroll
    for (int q = 0; q < 4; ++q) {
        union { u16 u[4]; uint2 v; } pk;
#pragma unroll
        for (int r = 0; r < 4; ++r) pk.u[r] = f2bf(a[4 * q + r]);
        *(uint2*)(T + Ar * 64 + c0 + q * 8) = pk.v;
    }
}

__device__ __forceinline__ void epiT32(fx16& a, const float* __restrict__ P,
                                       int TI, int TJ, int l, float qa, float qb) {
    const int gc = TJ * 32 + (l & 31);
    const int r0 = TI * 32 + 4 * (l >> 5);
#pragma unroll
    for (int q = 0; q < 4; ++q)
#pragma unroll
        for (int r = 0; r < 4; ++r) {
            const int gr = r0 + q * 8 + r;
            float m = (P[gc * 64 + gr] - P[gr * 64 + gc]) * 0.03125f;
            a[4 * q + r] += qb * m + (gr == gc ? qa : 0.f);
        }
}
__device__ __forceinline__ void epiN32(fx16& a, const float* __restrict__ P,
                                       int TI, int TJ, int l, float qa, float qb) {
    const int gc = TJ * 32 + (l & 31);
    const int r0 = TI * 32 + 4 * (l >> 5);
#pragma unroll
    for (int q = 0; q < 4; ++q)
#pragma unroll
        for (int r = 0; r < 4; ++r) {
            const int gr = r0 + q * 8 + r;
            float m = (P[gr * 64 + gc] - P[gc * 64 + gr]) * 0.03125f;
            a[4 * q + r] += qb * m + (gr == gc ? qa : 0.f);
        }
}

// K1: expm(P - P^T): scale 1/32, degree-9 PS-Horner, 5 squarings. One barrier/step.
__global__ __launch_bounds__(256) void expm_kernel(const float* __restrict__ praw,
                                                   u16* __restrict__ wsP)
{
    __shared__ u16 S[8 * PL];   // 4 hi/lo pairs = 73.7 KB
    const int g = blockIdx.x, tid = threadIdx.x;
    const int w = tid >> 6, l = tid & 63;
    const int ti = w & 1, tj = w >> 1;
    const float* P = praw + g * 4096;

    u16* p0h = S;            u16* p0l = S + PL;
    u16* p1h = S + 2 * PL;   u16* p1l = S + 3 * PL;
    u16* p2h = S + 4 * PL;   u16* p2l = S + 5 * PL;
    u16* p3h = S + 6 * PL;   u16* p3l = S + 7 * PL;

    for (int s = tid; s < 4096; s += 256) {
        const int r = s >> 6, c = s & 63;
        const float m = (P[r * 64 + c] - P[c * 64 + r]) * 0.03125f;
        u32 um = __float_as_uint(m);
        float lof = m - __uint_as_float(um & 0xFFFF0000u);
        u16 hh = (u16)(um >> 16), ll = f2bf(lof);
        p0h[r * LDW + c] = hh;  p0l[r * LDW + c] = ll;
        p1h[c * LDW + r] = hh;  p1l[c * LDW + r] = ll;
    }
    __syncthreads();

    fx16 acc, a1, a2;

    // step0: Q = M2 -> p2 (symmetric); R0 = C8 I + C9 M -> p3
    mmS(p1h, p1l, p0h, p0l, ti, tj, l, acc);
    stP(p2h, p2l, ti, tj, l, acc);
    {
        const float C8 = 2.48015873015873e-5f, C9 = 2.75573192239859e-6f;
        for (int s = tid; s < 4096; s += 256) {
            const int r = s >> 6, c = s & 63;
            float m = bf2f(p0h[r * LDW + c]) + bf2f(p0l[r * LDW + c]);
            float v = C9 * m + (r == c ? C8 : 0.f);
            u32 u = __float_as_uint(v);
            p3h[r * LDW + c] = (u16)(u >> 16);
            p3l[r * LDW + c] = f2bf(v - __uint_as_float(u & 0xFFFF0000u));
        }
    }
    __syncthreads();

    mmS(p2h, p2l, p3h, p3l, ti, tj, l, acc);
    epiT32(acc, P, ti, tj, l, 1.388888888888889e-3f, 1.984126984126984e-4f); // 1/720, 1/5040
    stP(p0h, p0l, ti, tj, l, acc);
    __syncthreads();
    mmS(p2h, p2l, p0h, p0l, ti, tj, l, acc);
    epiT32(acc, P, ti, tj, l, 4.166666666666667e-2f, 8.333333333333333e-3f); // 1/24, 1/120
    stP(p3h, p3l, ti, tj, l, acc);
    __syncthreads();
    mmS(p2h, p2l, p3h, p3l, ti, tj, l, acc);
    epiT32(acc, P, ti, tj, l, 0.5f, 1.666666666666667e-1f);                  // 1/2, 1/6
    stP(p0h, p0l, ti, tj, l, acc);
    __syncthreads();
    mmD(p2h, p2l, p0h, p0l, ti, tj, l, a1, a2);
    epiT32(a1, P, ti, tj, l, 1.f, 1.f);
    epiN32(a2, P, tj, ti, l, 1.f, 1.f);
    stP(p3h, p3l, ti, tj, l, a1);
    stP(p1h, p1l, tj, ti, l, a2);
    __syncthreads();

    u16 *Ych = p1h, *Ycl = p1l, *Xch = p3h, *Xcl = p3l;
    u16 *Ynh = p2h, *Ynl = p2l, *Xnh = p0h, *Xnl = p0l;
#pragma unroll 1
    for (int s5 = 0; s5 < 5; ++s5) {
        mmD(Ych, Ycl, Xch, Xcl, ti, tj, l, a1, a2);
        stP(Xnh, Xnl, ti, tj, l, a1);
        stP(Ynh, Ynl, tj, ti, l, a2);
        __syncthreads();
        u16* t;
        t = Xch; Xch = Xnh; Xnh = t;   t = Xcl; Xcl = Xnl; Xnl = t;
        t = Ych; Ych = Ynh; Ynh = t;   t = Ycl; Ycl = Ynl; Ynl = t;
    }

    for (int s8 = tid; s8 < 512; s8 += 256) {
        const int base = s8 * 8, r = base >> 6, c = base & 63;
        u16* dst = wsP + g * 16384;
        *(uint4*)(dst + base)         = *(const uint4*)(Ych + r * LDW + c);  // rm hi
        *(uint4*)(dst + 4096 + base)  = *(const uint4*)(Ycl + r * LDW + c);  // rm lo
        *(uint4*)(dst + 8192 + base)  = *(const uint4*)(Xch + r * LDW + c);  // cm hi
        *(uint4*)(dst + 12288 + base) = *(const uint4*)(Xcl + r * LDW + c);  // cm lo
    }
}

// K2: chain tables E(p), p in [0,64). One block per p, 4 waves, 32x32 MFMA.
__global__ __launch_bounds__(256) void table_kernel(const u16* __restrict__ wsP,
                                                    u16* __restrict__ rm_bf,
                                                    u16* __restrict__ cm_bf)
{
    __shared__ u16 S[8 * PL];
    const int p = blockIdx.x, tid = threadIdx.x;
    const int w = tid >> 6, l = tid & 63;
    const int ti = w & 1, tj = w >> 1;

    if (p < 2) {
        for (int s = tid; s < 4096; s += 256) {
            u16 v = ((s >> 6) == (s & 63)) ? (u16)0x3F80 : (u16)0;
            rm_bf[p * 4096 + s] = v;
            cm_bf[p * 4096 + s] = v;
        }
        return;
    }
    const int d = 31 - __clz(p);

    if (d == 1) {
        const u16* src = wsP + (p & 1) * 16384;
        for (int s = tid; s < 4096; s += 256) {
            rm_bf[p * 4096 + s] = f2bf(bf2f(src[s]) + bf2f(src[4096 + s]));
            cm_bf[p * 4096 + s] = f2bf(bf2f(src[8192 + s]) + bf2f(src[12288 + s]));
        }
        return;
    }

    u16* TAh = S;            u16* TAl = S + PL;       // cm(T0)
    u16* TBh = S + 2 * PL;   u16* TBl = S + 3 * PL;   // cm(T1)
    u16* Eah = S + 4 * PL;   u16* Eal = S + 5 * PL;   // E ping
    u16* Ebh = S + 6 * PL;   u16* Ebl = S + 7 * PL;   // E pong

    {
        const int b0 = p & 1;
        for (int s8 = tid; s8 < 512; s8 += 256) {
            const int base = s8 * 8, r = base >> 6, c = base & 63;
            *(uint4*)(TAh + r * LDW + c) = *(const uint4*)(wsP + 8192 + base);
            *(uint4*)(TAl + r * LDW + c) = *(const uint4*)(wsP + 12288 + base);
            *(uint4*)(TBh + r * LDW + c) = *(const uint4*)(wsP + 16384 + 8192 + base);
            *(uint4*)(TBl + r * LDW + c) = *(const uint4*)(wsP + 16384 + 12288 + base);
            *(uint4*)(Eah + r * LDW + c) = *(const uint4*)(wsP + b0 * 16384 + base);
            *(uint4*)(Eal + r * LDW + c) = *(const uint4*)(wsP + b0 * 16384 + 4096 + base);
        }
    }
    __syncthreads();

    fx16 acc, a1, a2;
    u16 *Ech = Eah, *Ecl = Eal, *Enh = Ebh, *Enl = Ebl;
#pragma unroll 1
    for (int j = 1; j <= d - 2; ++j) {
        const int b = (p >> j) & 1;
        mmS(b ? TBh : TAh, b ? TBl : TAl, Ech, Ecl, ti, tj, l, acc);
        stP(Enh, Enl, ti, tj, l, acc);
        __syncthreads();
        u16* t;
        t = Ech; Ech = Enh; Enh = t;   t = Ecl; Ecl = Enl; Enl = t;
    }
    {
        const int b = (p >> (d - 1)) & 1;
        mmD(b ? TBh : TAh, b ? TBl : TAl, Ech, Ecl, ti, tj, l, a1, a2);
        stG(rm_bf + p * 4096, ti, tj, l, a1);   // rm(E·T)
        stG(cm_bf + p * 4096, tj, ti, l, a2);   // cm(E·T)
    }
}

// K3: one wave per token. Content row + maps (copy or maps^T = E_hi^T · E_lo^T via MFMA).
// Plain stores (no NT): L2 merges the 64B half-line segments into full 128B lines.
__global__ __launch_bounds__(256) void out_kernel(const int* __restrict__ tt,
                                                  const int* __restrict__ tv,
                                                  const int* __restrict__ npos,
                                                  const float* __restrict__ embed,
                                                  const u16* __restrict__ rm_bf,
                                                  const u16* __restrict__ cm_bf,
                                                  float* __restrict__ out)
{
    const int tid = threadIdx.x;
    const int wv = tid >> 6, l = tid & 63;
    const int flat = blockIdx.x * 4 + wv;
    const int pos = npos[flat];

    {
        const int t = tt[flat], v = tv[flat];
        int idx; bool valid = true;
        if (t == 0)      idx = 0;
        else if (t == 1) idx = v + 1;
        else if (t == 2) idx = v + 5;
        else if (t == 4) idx = 8;
        else if (t == 3 && v == -1) idx = 10;
        else { idx = 0; valid = false; }
        out[flat * 64 + l] = valid ? embed[idx * 64 + l] : 0.f;
    }

    float* om = out + 4096 * 64 + (size_t)flat * 4096;

    if (pos < 64) {
        const u16* src = rm_bf + pos * 4096;
        for (int e = l * 8; e < 4096; e += 512) {
            uint4 ld = *(const uint4*)(src + e);
            fx4 lo, hi;
            lo[0] = __uint_as_float(ld.x << 16); lo[1] = __uint_as_float(ld.x & 0xFFFF0000u);
            lo[2] = __uint_as_float(ld.y << 16); lo[3] = __uint_as_float(ld.y & 0xFFFF0000u);
            hi[0] = __uint_as_float(ld.z << 16); hi[1] = __uint_as_float(ld.z & 0xFFFF0000u);
            hi[2] = __uint_as_float(ld.w << 16); hi[3] = __uint_as_float(ld.w & 0xFFFF0000u);
            *(fx4*)(om + e) = lo;
            *(fx4*)(om + e + 4) = hi;
        }
    } else {
        const int lo5 = (pos & 31) | 32;
        const int hi5 = pos >> 5;
        const u16* Acm = cm_bf + hi5 * 4096;
        const u16* Brm = rm_bf + lo5 * 4096;
        const int lr = l & 15, k8 = (l >> 4) * 8;

        bx8 A0[4], A1[4], B0[4], B1[4];
#pragma unroll
        for (int q = 0; q < 4; ++q) {
            A0[q] = *(const bx8*)(Acm + (q * 16 + lr) * 64 + k8);
            A1[q] = *(const bx8*)(Acm + (q * 16 + lr) * 64 + 32 + k8);
        }
#pragma unroll
        for (int c = 0; c < 4; ++c) {
            B0[c] = *(const bx8*)(Brm + (c * 16 + lr) * 64 + k8);
            B1[c] = *(const bx8*)(Brm + (c * 16 + lr) * 64 + 32 + k8);
        }
#pragma unroll
        for (int ct = 0; ct < 4; ++ct) {
#pragma unroll
            for (int q = 0; q < 4; ++q) {
                fx4 c4 = { 0.f, 0.f, 0.f, 0.f };
                c4 = __builtin_amdgcn_mfma_f32_16x16x32_bf16(A0[q], B0[ct], c4, 0, 0, 0);
                c4 = __builtin_amdgcn_mfma_f32_16x16x32_bf16(A1[q], B1[ct], c4, 0, 0, 0);
                *(fx4*)(om + (ct * 16 + lr) * 64 + q * 16 + 4 * (l >> 4)) = c4;
            }
        }
    }
}

extern "C" void kernel_launch(void* const* d_in, const int* in_sizes, int n_in,
                              void* d_out, int out_size, void* d_ws, size_t ws_size,
                              hipStream_t stream)
{
    const int*   tt    = (const int*)d_in[0];
    const int*   tv    = (const int*)d_in[1];
    const int*   np    = (const int*)d_in[2];
    const float* embed = (const float*)d_in[3];
    const float* praw  = (const float*)d_in[4];
    float* out = (float*)d_out;

    u16* wsP   = (u16*)d_ws;
    u16* rm_bf = (u16*)((char*)d_ws + 65536);
    u16* cm_bf = (u16*)((char*)d_ws + 65536 + 524288);

    expm_kernel<<<dim3(2), dim3(256), 0, stream>>>(praw, wsP);
    table_kernel<<<dim3(64), dim3(256), 0, stream>>>(wsP, rm_bf, cm_bf);
    out_kernel<<<dim3(1024), dim3(256), 0, stream>>>(tt, tv, np, embed, rm_bf, cm_bf, out);
}